// Round 13
// baseline (234.623 us; speedup 1.0000x reference)
//
#include <hip/hip_runtime.h>
#include <math.h>

// QuantizedAttention: B=2, S=2048, D=1024, H=16, Dh=64.
// Round 18:
//  - r17 CONFIRMED: setprio helped flash (<46.3us, out of top-5); best 223.7.
//  - gemm3 diagnosis: 2320 cyc per BK64-step/CU vs ~700 for MFMA+reads ->
//    staging drain fully exposed (loads issued right before vmcnt(0)+barrier).
//  - FIX: double-buffered staging, BK=32: per K-step {barrier (drains PREV
//    prefetch) -> issue gll16 for t+1 into buf^1 -> compute t}. Load latency
//    overlaps the whole compute phase. BK32 stride-64B layout is naturally
//    ~2-way (free) -> XOR swizzle dropped. LDS: gemm3 32KB staging (34816B
//    total incl. MODE3 transpose union, occupancy unchanged 3/CU; avoids
//    m132's 64KB BK64-dbuf cliff); gemm_wo 24KB.
//  - flash (r17: mfma9+setprio), prep1/prep2, XCD remap, rotary/vT fusion
//    all byte-identical to round 17.

typedef __attribute__((ext_vector_type(8))) short bf16x8;   // 8 bf16 = 4 VGPRs
typedef __attribute__((ext_vector_type(16))) float f32x16;
typedef __attribute__((ext_vector_type(4))) float f32x4;
typedef __attribute__((ext_vector_type(4))) float f4;

#define E4M3_MAX 448.0f

__device__ inline float bf2f(ushort u) { return __uint_as_float(((unsigned)u) << 16); }
__device__ inline ushort f2bf(float f) {
  unsigned u = __float_as_uint(f);
  return (ushort)((u + 0x7FFF + ((u >> 16) & 1)) >> 16);  // RNE
}
__device__ inline unsigned pack2bf(float a, float b) {  // round-half-up
  unsigned ua = __float_as_uint(a), ub = __float_as_uint(b);
  return ((ua + 0x8000u) >> 16) | ((ub + 0x8000u) & 0xFFFF0000u);
}

// async 16B global -> LDS (direct-to-shared DMA). LDS dest must be
// wave-uniform base + lane*16 — all call sites below satisfy that.
__device__ __forceinline__ void gll16(const ushort* g, ushort* l) {
  __builtin_amdgcn_global_load_lds(
      (const __attribute__((address_space(1))) unsigned int*)g,
      (__attribute__((address_space(3))) unsigned int*)l, 16, 0, 0);
}

// e4m3 GRID value (no descale) -- exactly representable in bf16.
__device__ inline float qdq_qval(float w, float amax) {
  float scale = E4M3_MAX / fmaxf(amax, 1e-12f);
  float v = w * scale;
  float a = fmaxf(fabsf(v), 1e-30f);
  int ex;
  (void)frexpf(a, &ex);                 // floor(log2(a)) = ex-1
  float e = fminf(fmaxf((float)(ex - 1), -6.0f), 8.0f);
  float step = exp2f(e - 3.0f);
  float q = rintf(v / step) * step;     // round-half-even matches jnp.round
  return fminf(fmaxf(q, -E4M3_MAX), E4M3_MAX);
}

// all-lanes max of amaxpart[off + 0..63] (wave64 shuffle reduce, no LDS).
__device__ __forceinline__ float redpart64(const float* __restrict__ p, int tid) {
  float v = p[tid & 63];
  #pragma unroll
  for (int o = 32; o > 0; o >>= 1) v = fmaxf(v, __shfl_xor(v, o));
  return v;
}

// ---- prep1: bid<384 -> amax partial maxes (y=bid/64); else cvt3 fp32->bf16.
__global__ __launch_bounds__(256) void prep1(const float* __restrict__ W0,
                                             const float* __restrict__ W1,
                                             const float* __restrict__ W2,
                                             const float* __restrict__ b0,
                                             const float* __restrict__ b1,
                                             const float* __restrict__ b2,
                                             const float* __restrict__ Xq,
                                             const float* __restrict__ Xk,
                                             const float* __restrict__ Xv,
                                             float* __restrict__ amaxpart,
                                             ushort* __restrict__ xq,
                                             ushort* __restrict__ xk,
                                             ushort* __restrict__ xv) {
  __shared__ float wred[4];
  int bid = blockIdx.x, tid = threadIdx.x;
  if (bid < 384) {
    int y = bid >> 6, xb = bid & 63;
    const float* src = (y == 0) ? W0 : (y == 1) ? W1 : (y == 2) ? W2
                     : (y == 3) ? b0 : (y == 4) ? b1 : b2;
    int n = (y < 3) ? 1048576 : 1024;
    float m = 0.0f;
    for (int i = xb * 256 + tid; i < n; i += 64 * 256)
      m = fmaxf(m, fabsf(src[i]));
    #pragma unroll
    for (int off = 32; off > 0; off >>= 1)
      m = fmaxf(m, __shfl_xor(m, off));
    if ((tid & 63) == 0) wred[tid >> 6] = m;
    __syncthreads();
    if (tid == 0)
      amaxpart[y * 64 + xb] = fmaxf(fmaxf(wred[0], wred[1]), fmaxf(wred[2], wred[3]));
  } else {
    int t = bid - 384;
    int y = t >> 12, xb = t & 4095;
    const float* in = (y == 0) ? Xq : (y == 1) ? Xk : Xv;
    ushort* out = (y == 0) ? xq : (y == 1) ? xk : xv;
    int i = xb * 256 + tid;
    f4 v = *(const f4*)(in + (size_t)i * 4);
    uint2 o;
    o.x = (unsigned)f2bf(v[0]) | ((unsigned)f2bf(v[1]) << 16);
    o.y = (unsigned)f2bf(v[2]) | ((unsigned)f2bf(v[3]) << 16);
    *(uint2*)(out + (size_t)i * 4) = o;
  }
}

// ---- prep2: bid<768 repack W->Bt; bid<780 qvec bias; else wo_trans.
__global__ __launch_bounds__(256) void prep2(const float* __restrict__ W0,
                                             const float* __restrict__ W1,
                                             const float* __restrict__ W2,
                                             const float* __restrict__ WO,
                                             const float* __restrict__ b0,
                                             const float* __restrict__ b1,
                                             const float* __restrict__ b2,
                                             const float* __restrict__ amaxpart,
                                             float* __restrict__ amax,
                                             ushort* __restrict__ o0,
                                             ushort* __restrict__ o1,
                                             ushort* __restrict__ o2,
                                             ushort* __restrict__ woT,
                                             float* __restrict__ bq,
                                             float* __restrict__ bk,
                                             float* __restrict__ bv) {
  __shared__ float tile[64][65];
  int bid = blockIdx.x, tid = threadIdx.x;
  if (bid < 768) {
    int z = bid >> 8, r = bid & 255, hh = r >> 4, xb = r & 15;
    const float* W = (z == 0) ? W0 : (z == 1) ? W1 : W2;
    ushort* Bt = (z == 0) ? o0 : (z == 1) ? o1 : o2;
    float am = redpart64(amaxpart + z * 64, tid);
    if (r == 0 && tid == 0) amax[z] = am;   // final for gemm3_qkv (next launch)
    int d0 = xb * 64;
    int e = tid & 63, dd = tid >> 6;
    #pragma unroll
    for (int p = 0; p < 16; p++)
      tile[dd + p * 4][e] = W[(size_t)hh * 65536 + (size_t)(d0 + dd + p * 4) * 64 + e];
    __syncthreads();
    int d = tid & 63, ee = tid >> 6;
    #pragma unroll
    for (int p = 0; p < 16; p++) {
      int e2 = ee + p * 4;
      Bt[(size_t)(hh * 64 + e2) * 1024 + d0 + d] = f2bf(qdq_qval(tile[d][e2], am));
    }
  } else if (bid < 780) {
    int q = bid - 768, y = q >> 2, xb = q & 3;
    const float* b = (y == 0) ? b0 : (y == 1) ? b1 : b2;
    float* o = (y == 0) ? bq : (y == 1) ? bk : bv;
    float am = redpart64(amaxpart + (3 + y) * 64, tid);
    int idx = xb * 256 + tid;
    if (idx < 1024) {
      float qv = qdq_qval(b[idx], am);
      o[idx] = qv * (fmaxf(am, 1e-12f) * (1.0f / E4M3_MAX));
    }
  } else {
    int t = bid - 780;
    int xb = t & 15, yb = t >> 4;
    int d0 = xb * 64, he0 = yb * 64;
    int dcol = tid & 63, hr = tid >> 6;
    #pragma unroll
    for (int p = 0; p < 16; p++)
      tile[hr + p * 4][dcol] = WO[(size_t)(he0 + hr + p * 4) * 1024 + d0 + dcol];
    __syncthreads();
    int hcol = tid & 63, dr = tid >> 6;
    #pragma unroll
    for (int p = 0; p < 16; p++)
      woT[(size_t)(d0 + dr + p * 4) * 1024 + he0 + hcol] = f2bf(tile[hcol][dr + p * 4]);
  }
}

// GEMM body: C = A[M=4096][K=1024] x Bt[N][K]^T, tile 128 x TN, BK=32,
// DOUBLE-BUFFERED staging: per K-step {barrier (drains prev prefetch) ->
// issue gll16 for t+1 into buf^1 -> compute t}. One barrier per step; the
// vmcnt(0)-before-barrier waits on loads that aged a full compute phase.
// BK32 stride-64B LDS layout: ~2-way bank alias (free, m136) -> no swizzle.
// As = 2*4096 ushorts (buf0|buf1); Bs = 2*(TN*32) ushorts.
// MODE 0: out fp32 +bias.  MODE 2: out bf16 *s_inv+bias, fused rotary (q/k).
// MODE 3: out bf16 *s_inv+bias, TRANSPOSED to vT (As region reused as
//         128*136-ushort transpose buffer = 34816 B).
template <int MODE, int TN>
__device__ __forceinline__ void gemm_body(const ushort* __restrict__ A,
                                          const ushort* __restrict__ Bt,
                                          const float* __restrict__ bias, float s_inv,
                                          ushort* __restrict__ outb, float* __restrict__ outf,
                                          int bx, int by, ushort* As, ushort* Bs) {
  const int K = 1024, N = 1024;
  const int JF = TN / 32;                 // j-frags per wave
  const int ABUF = 4096;                  // ushorts per A buffer (128x32)
  const int BBUF = TN * 32;               // ushorts per B buffer (TNx32)
  int tid = threadIdx.x;
  int w = tid >> 6, lane = tid & 63, quad = lane >> 4, l16 = lane & 15;
  int wm = w & 1, wn = w >> 1;
  int row0 = by * 128, col0 = bx * TN;
  f32x4 acc[4][4] = {};

  {                                       // prologue: stage k0=0 into buf0
    int u = tid;
    gll16(&A[(size_t)(row0 + (u >> 2)) * K + (u & 3) * 8], &As[u * 8]);
    u = tid + 256;
    gll16(&A[(size_t)(row0 + (u >> 2)) * K + (u & 3) * 8], &As[u * 8]);
    u = tid;
    gll16(&Bt[(size_t)(col0 + (u >> 2)) * K + (u & 3) * 8], &Bs[u * 8]);
    if (TN == 128) {
      u = tid + 256;
      gll16(&Bt[(size_t)(col0 + (u >> 2)) * K + (u & 3) * 8], &Bs[u * 8]);
    }
  }

  for (int t = 0; t < 32; t++) {
    const int cur = t & 1;
    __syncthreads();                      // drains own gll16 (cur buf) + barrier
    if (t + 1 < 32) {                     // prefetch t+1 into buf^1 (in flight
      const int nb = cur ^ 1;             //  across the whole compute phase)
      int k0 = (t + 1) * 32;
      int u = tid;
      gll16(&A[(size_t)(row0 + (u >> 2)) * K + k0 + (u & 3) * 8], &As[nb * ABUF + u * 8]);
      u = tid + 256;
      gll16(&A[(size_t)(row0 + (u >> 2)) * K + k0 + (u & 3) * 8], &As[nb * ABUF + u * 8]);
      u = tid;
      gll16(&Bt[(size_t)(col0 + (u >> 2)) * K + k0 + (u & 3) * 8], &Bs[nb * BBUF + u * 8]);
      if (TN == 128) {
        u = tid + 256;
        gll16(&Bt[(size_t)(col0 + (u >> 2)) * K + k0 + (u & 3) * 8], &Bs[nb * BBUF + u * 8]);
      }
    }
    const ushort* Ac = As + cur * ABUF;
    const ushort* Bc = Bs + cur * BBUF;
    bf16x8 af[4], bfr[JF];
    #pragma unroll
    for (int i = 0; i < 4; i++)
      af[i] = *(const bf16x8*)&Ac[(wm * 64 + i * 16 + l16) * 32 + quad * 8];
    #pragma unroll
    for (int j = 0; j < JF; j++)
      bfr[j] = *(const bf16x8*)&Bc[(wn * (TN / 2) + j * 16 + l16) * 32 + quad * 8];
    #pragma unroll
    for (int i = 0; i < 4; i++)
      #pragma unroll
      for (int j = 0; j < JF; j++)
        acc[i][j] = __builtin_amdgcn_mfma_f32_16x16x32_bf16(af[i], bfr[j], acc[i][j], 0, 0, 0);
  }

  if (MODE == 2) {
    // fused rotary (TN=128): e = j*16+l16; partner frag j+2 (e+32);
    // inv_freq indexed by e&31 = jp*16+l16, identical for both partners.
    float bv0[4];
    #pragma unroll
    for (int j = 0; j < 4; j++) bv0[j] = bias[col0 + wn * 64 + j * 16 + l16];
    #pragma unroll
    for (int jp = 0; jp < 2; jp++) {
      float invf = exp2f((float)(jp * 16 + l16) * (-13.287712379549449f / 32.0f));
      int collo = col0 + wn * 64 + jp * 16 + l16;
      #pragma unroll
      for (int i = 0; i < 4; i++) {
        #pragma unroll
        for (int r = 0; r < 4; r++) {
          int row = row0 + wm * 64 + i * 16 + quad * 4 + r;
          float ang = (float)(row & 2047) * invf;
          float sn = __sinf(ang), c = __cosf(ang);
          float lo = acc[i][jp][r] * s_inv + bv0[jp];
          float hi = acc[i][jp + 2][r] * s_inv + bv0[jp + 2];
          outb[(size_t)row * N + collo] = f2bf(lo * c - hi * sn);
          outb[(size_t)row * N + collo + 32] = f2bf(hi * c + lo * sn);
        }
      }
    }
  } else if (MODE == 3) {
    // v-transpose epilogue: bf16 v-tile -> LDS [colL][rowL] (stride 136),
    // then coalesced store to vT[(b*1024+he)][s]. outb = vT base.
    __syncthreads();                      // all waves done with K-loop LDS reads
    ushort* sb = As;                      // 128 x 136 ushorts
    #pragma unroll
    for (int j = 0; j < JF; j++) {
      int colL = wn * (TN / 2) + j * 16 + l16;
      float bv = bias[col0 + colL];
      #pragma unroll
      for (int i = 0; i < 4; i++) {
        int rowL = wm * 64 + i * 16 + quad * 4;
        uint2 o;
        o.x = (unsigned)f2bf(acc[i][j][0] * s_inv + bv) |
              ((unsigned)f2bf(acc[i][j][1] * s_inv + bv) << 16);
        o.y = (unsigned)f2bf(acc[i][j][2] * s_inv + bv) |
              ((unsigned)f2bf(acc[i][j][3] * s_inv + bv) << 16);
        *(uint2*)&sb[colL * 136 + rowL] = o;
      }
    }
    __syncthreads();
    int bb = row0 >> 11, sloc = row0 & 2047;
    #pragma unroll
    for (int p = 0; p < 8; p++) {         // 2048 uint4s: 128 rows x 16 chunks
      int u = tid + p * 256;
      int r = u >> 4, cc = u & 15;
      *(uint4*)&outb[(size_t)(bb * 1024 + col0 + r) * 2048 + sloc + cc * 8] =
          *(const uint4*)&sb[r * 136 + cc * 8];
    }
  } else {
    #pragma unroll
    for (int j = 0; j < JF; j++) {
      int col = col0 + wn * (TN / 2) + j * 16 + l16;
      float bv = bias[col];
      #pragma unroll
      for (int i = 0; i < 4; i++) {
        int row = row0 + wm * 64 + i * 16 + quad * 4;
        #pragma unroll
        for (int r = 0; r < 4; r++)
          outf[(size_t)(row + r) * N + col] = acc[i][j][r] * s_inv + bv;
      }
    }
  }
}

// Batched QKV projection: 1D grid 768, XCD-remapped so the 8 blocks sharing
// an A-panel (same by,z) have bid===const (mod 8) -> one XCD's L2.
// z<2: rotary epilogue -> qbf/kbf. z=2: transpose epilogue -> vT.
__global__ __launch_bounds__(256) void gemm3_qkv(const ushort* __restrict__ xq,
                                                 const ushort* __restrict__ xk,
                                                 const ushort* __restrict__ xv,
                                                 const ushort* __restrict__ wq,
                                                 const ushort* __restrict__ wk,
                                                 const ushort* __restrict__ wv,
                                                 const float* __restrict__ bq,
                                                 const float* __restrict__ bk,
                                                 const float* __restrict__ bv,
                                                 const float* __restrict__ amax,
                                                 ushort* __restrict__ oq,
                                                 ushort* __restrict__ ok,
                                                 ushort* __restrict__ vT) {
  // As dbuf 2x4096 | Bs dbuf 2x4096 = 16384 ushorts; MODE3 reuses 17408.
  __shared__ __align__(16) ushort sb[17408];
  ushort* As = sb;
  ushort* Bs = sb + 8192;
  int bid = blockIdx.x;
  int rr = bid & 7, t = bid >> 3;
  int bx = t & 7, gq = rr + 8 * (t >> 3);      // gq = by + 32*z, gq%8 == rr
  int by = gq & 31, z = gq >> 5;
  const ushort* A  = (z == 0) ? xq : (z == 1) ? xk : xv;
  const ushort* Bt = (z == 0) ? wq : (z == 1) ? wk : wv;
  const float* bias = (z == 0) ? bq : (z == 1) ? bk : bv;
  float s_inv = fmaxf(amax[z], 1e-12f) * (1.0f / E4M3_MAX);
  if (z == 2)
    gemm_body<3, 128>(A, Bt, bias, s_inv, vT, nullptr, bx, by, As, Bs);
  else
    gemm_body<2, 128>(A, Bt, bias, s_inv, (z == 0) ? oq : ok, nullptr, bx, by, As, Bs);
}

// Output projection: 1D grid 512 (128x64 tiles), XCD-remapped (same-by
// blocks co-located: 16 bx per by).
__global__ __launch_bounds__(256) void gemm_wo(const ushort* __restrict__ A,
                                               const ushort* __restrict__ Bt,
                                               const float* __restrict__ bias,
                                               float* __restrict__ out) {
  __shared__ __align__(16) ushort As[8192], Bs[4096];   // dbuf: 2x4096 | 2x2048
  int bid = blockIdx.x;
  int rr = bid & 7, t = bid >> 3;
  int bx = t & 15, by = rr + 8 * (t >> 4);
  gemm_body<0, 64>(A, Bt, bias, 1.0f, nullptr, out, bx, by, As, Bs);
}

// ---- Flash v9 (r17 VERBATIM: r15 body + setprio, measured <46.3us).
// Grid (16,16,2) = 512 blocks, 512 thr / 8 waves, one q-tile per block,
// qt = bz ? 15-bx : bx. Co-resident blocks (i, i+256) have 17 block-iters
// total -> uniform per-CU work in two independent 8-wave barrier groups.
__global__ __launch_bounds__(512, 4) void flash_mfma9(const ushort* __restrict__ qb,
                                                      const ushort* __restrict__ kb,
                                                      const ushort* __restrict__ vT,
                                                      ushort* __restrict__ zb) {
  int h = blockIdx.y, b = blockIdx.z;
  int tid = threadIdx.x;
  int w8 = tid >> 6;                     // 0..7
  int g = w8 >> 2;                       // kv split
  int w = w8 & 3;                        // q-wave within split
  int lane = tid & 63, h2 = lane >> 5, l31 = lane & 31;
  // LDS (ushorts): Ks[2][4096] | Vs[2][4096] | P2[2][9216]  = 69632 B
  __shared__ ushort sbuf[16384 + 18432];
  ushort* Ks = sbuf + g * 4096;
  ushort* Vs = sbuf + 8192 + g * 4096;
  ushort* P2 = sbuf + 16384 + g * 9216;

  const int qrow = w * 32 + l31;         // block-local q row in P2
  const float CE = 0.125f;               // 1/sqrt(64)

  // staging geometry (per split: 256 threads stage 64x64 K and V tiles)
  const int ts = tid & 255;
  const int u0 = ts, u1 = ts + 256;
  const int r0 = u0 >> 3, c0 = u0 & 7, r1 = u1 >> 3, c1 = u1 & 7;
  const int sw0 = (c0 ^ (r0 & 7)) * 8, sw1 = (c1 ^ (r1 & 7)) * 8;

  const int qt = (blockIdx.z == 0) ? (int)blockIdx.x : 15 - (int)blockIdx.x;
  const int q0 = qt * 128;
  const int qg = q0 + w * 32 + l31;      // this lane's q (column of S^T)
  size_t qbase = ((size_t)(b * 2048 + qg)) * 1024 + (size_t)h * 64;
  bf16x8 qf[4];                          // Q B-frags: slot (h2,j) of chunk ck <- e=16ck+8h2+j
  #pragma unroll
  for (int ck = 0; ck < 4; ck++)
    qf[ck] = *(const bf16x8*)&qb[qbase + ck * 16 + h2 * 8];

  f32x16 accO[2] = {};                   // O^T: rows e (2 frags), col q
  float mrun = -INFINITY, lrun = 0.0f;

  const int nt = qt + 1;                 // kv tiles per split (equal halves)
  const int kt0 = g * nt;                // first global kv tile of this split

  const ushort* ksrc0 = kb + ((size_t)(b * 2048 + kt0 * 64 + r0)) * 1024 + (size_t)h * 64 + c0 * 8;
  const ushort* ksrc1 = kb + ((size_t)(b * 2048 + kt0 * 64 + r1)) * 1024 + (size_t)h * 64 + c1 * 8;
  const ushort* vsrc0 = vT + ((size_t)((b * 16 + h) * 64 + r0)) * 2048 + kt0 * 64 + c0 * 8;
  const ushort* vsrc1 = vT + ((size_t)((b * 16 + h) * 64 + r1)) * 2048 + kt0 * 64 + c1 * 8;

  uint4 kc0 = *(const uint4*)ksrc0;      // prefetch tile 0 of this split
  uint4 kc1 = *(const uint4*)ksrc1;
  uint4 vc0 = *(const uint4*)vsrc0;
  uint4 vc1 = *(const uint4*)vsrc1;

  for (int t = 0; t < nt; t++) {
    int kt = kt0 + t;                    // global kv tile index
    __syncthreads();                     // prev iter's LDS reads done
    *(uint4*)&Ks[r0 * 64 + sw0] = kc0;
    *(uint4*)&Ks[r1 * 64 + sw1] = kc1;
    *(uint4*)&Vs[r0 * 64 + sw0] = vc0;
    *(uint4*)&Vs[r1 * 64 + sw1] = vc1;
    __syncthreads();
    if (t + 1 < nt) {                    // prefetch kt+1; in flight across compute
      kc0 = *(const uint4*)(ksrc0 + (size_t)(t + 1) * 65536);
      kc1 = *(const uint4*)(ksrc1 + (size_t)(t + 1) * 65536);
      vc0 = *(const uint4*)(vsrc0 + (t + 1) * 64);
      vc1 = *(const uint4*)(vsrc1 + (t + 1) * 64);
    }

    bool active = (kt * 64 <= q0 + w * 32 + 31);  // wave-uniform
    if (active) {
      // S^T = K . Q^T   (M=kv 2 frags of 32, K=e in 4 chunks of 16)
      f32x16 sc[2] = {};
      __builtin_amdgcn_s_setprio(1);
      #pragma unroll
      for (int mf = 0; mf < 2; mf++) {
        int row = mf * 32 + l31;
        int s8 = row & 7;
        #pragma unroll
        for (int ck = 0; ck < 4; ck++) {
          bf16x8 ka = *(const bf16x8*)&Ks[row * 64 + (((2 * ck + h2) ^ s8) * 8)];
          sc[mf] = __builtin_amdgcn_mfma_f32_32x32x16_bf16(ka, qf[ck], sc[mf], 0, 0, 0);
        }
      }
      __builtin_amdgcn_s_setprio(0);

      // causal mask (raw domain: -8000 * 0.125 = -1000 matches ref IGNORE)
      if (kt * 64 + 63 > q0 + w * 32) {
        #pragma unroll
        for (int mf = 0; mf < 2; mf++)
          #pragma unroll
          for (int i = 0; i < 16; i++) {
            int kv = kt * 64 + mf * 32 + (i & 3) + 8 * (i >> 2) + 4 * h2;
            sc[mf][i] = (kv > qg) ? -8000.0f : sc[mf][i];
          }
      }

      // online softmax: in-register (32 values/lane) + one xor-32 shuffle
      float tm = sc[0][0];
      #pragma unroll
      for (int i = 1; i < 16; i++) tm = fmaxf(tm, sc[0][i]);
      #pragma unroll
      for (int i = 0; i < 16; i++) tm = fmaxf(tm, sc[1][i]);
      tm = fmaxf(tm, __shfl_xor(tm, 32));
      float mnew = fmaxf(mrun, tm);
      float alpha = __expf((mrun - mnew) * CE);
      float p[2][16];
      float rs = 0.0f;
      #pragma unroll
      for (int mf = 0; mf < 2; mf++)
        #pragma unroll
        for (int i = 0; i < 16; i++) {
          float pv = __expf((sc[mf][i] - mnew) * CE);
          p[mf][i] = pv;
          rs += pv;
        }
      rs += __shfl_xor(rs, 32);
      lrun = lrun * alpha + rs;
      mrun = mnew;
      #pragma unroll
      for (int mf = 0; mf < 2; mf++)
        #pragma unroll
        for (int i = 0; i < 16; i++) accO[mf][i] *= alpha;

      // write P^T -> LDS as P2[q][kv]: lane owns row q=qrow (wave-private)
      #pragma unroll
      for (int mf = 0; mf < 2; mf++)
        #pragma unroll
        for (int m = 0; m < 4; m++) {
          uint2 w2;
          w2.x = pack2bf(p[mf][4 * m + 0], p[mf][4 * m + 1]);
          w2.y = pack2bf(p[mf][4 * m + 2], p[mf][4 * m + 3]);
          *(uint2*)&P2[qrow * 72 + 32 * mf + 8 * m + 4 * h2] = w2;
        }

      // O^T += V^T . P^T ; same-wave P2 read (compiler inserts lgkmcnt)
      __builtin_amdgcn_s_setprio(1);
      #pragma unroll
      for (int ck = 0; ck < 4; ck++) {
        bf16x8 pB = *(const bf16x8*)&P2[qrow * 72 + ck * 16 + h2 * 8];
        #pragma unroll
        for (int mf = 0; mf < 2; mf++) {
          int row = mf * 32 + l31;
          bf16x8 va = *(const bf16x8*)&Vs[row * 64 + (((2 * ck + h2) ^ (row & 7)) * 8)];
          accO[mf] = __builtin_amdgcn_mfma_f32_32x32x16_bf16(va, pB, accO[mf], 0, 0, 0);
        }
      }
      __builtin_amdgcn_s_setprio(0);
    }
  }

  // ---- merge the two kv-splits: log-sum-exp combine through LDS ----
  __syncthreads();                       // all compute done, LDS free
  float* mbuf = (float*)sbuf;            // 256 lanes x 35 floats (stride 35: 2-way banks)
  int midx = (w * 64 + lane) * 35;
  if (g == 1) {
    #pragma unroll
    for (int i = 0; i < 16; i++) mbuf[midx + i] = accO[0][i];
    #pragma unroll
    for (int i = 0; i < 16; i++) mbuf[midx + 16 + i] = accO[1][i];
    mbuf[midx + 32] = mrun;
    mbuf[midx + 33] = lrun;
  }
  __syncthreads();
  ushort* Osb = sbuf + 16384 + 9216;     // P2 split-1 region (past mbuf), 128 x 72
  if (g == 0) {
    float m1 = mbuf[midx + 32], l1 = mbuf[midx + 33];
    float mn = fmaxf(mrun, m1);
    float a0 = __expf((mrun - mn) * CE), a1 = __expf((m1 - mn) * CE);
    float linv = 1.0f / (lrun * a0 + l1 * a1);
    #pragma unroll
    for (int mf = 0; mf < 2; mf++)
      #pragma unroll
      for (int m = 0; m < 4; m++) {
        int e0 = 32 * mf + 8 * m + 4 * h2;
        float o0 = (accO[mf][4 * m + 0] * a0 + mbuf[midx + 16 * mf + 4 * m + 0] * a1) * linv;
        float o1 = (accO[mf][4 * m + 1] * a0 + mbuf[midx + 16 * mf + 4 * m + 1] * a1) * linv;
        float o2 = (accO[mf][4 * m + 2] * a0 + mbuf[midx + 16 * mf + 4 * m + 2] * a1) * linv;
        float o3 = (accO[mf][4 * m + 3] * a0 + mbuf[midx + 16 * mf + 4 * m + 3] * a1) * linv;
        *(unsigned*)&Osb[qrow * 72 + e0] = pack2bf(o0, o1);
        *(unsigned*)&Osb[qrow * 72 + e0 + 2] = pack2bf(o2, o3);
      }
  }
  __syncthreads();
  size_t obase = ((size_t)(b * 2048 + q0)) * 1024 + (size_t)h * 64;
  #pragma unroll
  for (int i = 0; i < 2; i++) {
    int u = tid + i * 512;               // 1024 units: 128 rows x 8 blocks
    int r = u >> 3, blk = u & 7;
    *(uint4*)&zb[obase + (size_t)r * 1024 + blk * 8] = *(const uint4*)&Osb[r * 72 + blk * 8];
  }
}

extern "C" void kernel_launch(void* const* d_in, const int* in_sizes, int n_in,
                              void* d_out, int out_size, void* d_ws, size_t ws_size,
                              hipStream_t stream) {
  const float* Xq  = (const float*)d_in[0];
  const float* Xk  = (const float*)d_in[1];
  const float* Xv  = (const float*)d_in[2];
  const float* W_Q = (const float*)d_in[3];
  const float* W_K = (const float*)d_in[4];
  const float* W_V = (const float*)d_in[5];
  const float* W_O = (const float*)d_in[6];
  const float* b_Q = (const float*)d_in[7];
  const float* b_K = (const float*)d_in[8];
  const float* b_V = (const float*)d_in[9];
  const float* b_O = (const float*)d_in[10];
  float* out = (float*)d_out;

  // ws layout (56.4 MB): amax/amaxpart/bias | weights 8.4MB | xq,xk,xv | qbf,kbf,vT
  // vT lives in the old vbf slot (vbf never materialized: gemm3 z=2 writes
  // vT directly). zbf overlays xk (dead after gemm3).
  char* base = (char*)d_ws;
  float*  amax = (float*)(base + 0);
  float*  amaxpart = (float*)(base + 1024);   // 6*64 floats = 1536 B
  float*  bq   = (float*)(base + 4096);
  float*  bk   = (float*)(base + 8192);
  float*  bv   = (float*)(base + 12288);
  ushort* wq   = (ushort*)(base + 16384);
  ushort* wk   = (ushort*)(base + 16384 + 2097152);
  ushort* wv   = (ushort*)(base + 16384 + 2u * 2097152);
  ushort* woT  = (ushort*)(base + 16384 + 3u * 2097152);
  ushort* xq   = (ushort*)(base + 8404992);
  ushort* xk   = (ushort*)(base + 16793600);
  ushort* xv   = (ushort*)(base + 25182208);
  ushort* qbf  = (ushort*)(base + 33570816);
  ushort* kbf  = (ushort*)(base + 41959424);
  ushort* vT   = (ushort*)(base + 50348032);  // old vbf slot
  ushort* zbf  = xk;   // xk dead after gemm3_qkv

  // 1) amax partials (384 blocks) + fp32->bf16 convert (12288 blocks)
  prep1<<<12672, 256, 0, stream>>>(W_Q, W_K, W_V, b_Q, b_K, b_V, Xq, Xk, Xv,
                                   amaxpart, xq, xk, xv);
  // 2) weight repack (768) + bias quant (12) + W_O transpose (256)
  prep2<<<1036, 256, 0, stream>>>(W_Q, W_K, W_V, W_O, b_Q, b_K, b_V,
                                  amaxpart, amax, wq, wk, wv, woT, bq, bk, bv);
  // 3) batched QKV GEMM: dbuf staging + fused rotary (q,k) + fused
  //    V-transpose (v), XCD-remapped
  gemm3_qkv<<<768, 256, 0, stream>>>(xq, xk, xv, wq, wk, wv, bq, bk, bv, amax,
                                     qbf, kbf, vT);
  // 4) flash attention: balanced 2-blocks/CU + setprio (r17-verified)
  dim3 fgrid(16, 16, 2);
  flash_mfma9<<<fgrid, 512, 0, stream>>>(qbf, kbf, vT, zbf);
  // 5) output projection: dbuf staging, XCD-remapped
  gemm_wo<<<512, 256, 0, stream>>>(zbf, woT, b_O, out);
}

// Round 14
// 228.373 us; speedup vs baseline: 1.0274x; 1.0274x over previous
//
#include <hip/hip_runtime.h>
#include <math.h>

// QuantizedAttention: B=2, S=2048, D=1024, H=16, Dh=64.
// Round 19 (corrected): unbundle r18 — gemm3 keeps dbuf BK32 (r18: <=44.6us),
// gemm_wo reverts to r17's BK64+swizzle (verified in 223.7 run). Flash r17
// verbatim. Predicted total ~220-223.

typedef __attribute__((ext_vector_type(8))) short bf16x8;
typedef __attribute__((ext_vector_type(16))) float f32x16;
typedef __attribute__((ext_vector_type(4))) float f32x4;
typedef __attribute__((ext_vector_type(4))) float f4;

#define E4M3_MAX 448.0f

__device__ inline float bf2f(ushort u) { return __uint_as_float(((unsigned)u) << 16); }
__device__ inline ushort f2bf(float f) {
  unsigned u = __float_as_uint(f);
  return (ushort)((u + 0x7FFF + ((u >> 16) & 1)) >> 16);  // RNE
}
__device__ inline unsigned pack2bf(float a, float b) {
  unsigned ua = __float_as_uint(a), ub = __float_as_uint(b);
  return ((ua + 0x8000u) >> 16) | ((ub + 0x8000u) & 0xFFFF0000u);
}

__device__ __forceinline__ void gll16(const ushort* g, ushort* l) {
  __builtin_amdgcn_global_load_lds(
      (const __attribute__((address_space(1))) unsigned int*)g,
      (__attribute__((address_space(3))) unsigned int*)l, 16, 0, 0);
}

__device__ inline float qdq_qval(float w, float amax) {
  float scale = E4M3_MAX / fmaxf(amax, 1e-12f);
  float v = w * scale;
  float a = fmaxf(fabsf(v), 1e-30f);
  int ex;
  (void)frexpf(a, &ex);
  float e = fminf(fmaxf((float)(ex - 1), -6.0f), 8.0f);
  float step = exp2f(e - 3.0f);
  float q = rintf(v / step) * step;
  return fminf(fmaxf(q, -E4M3_MAX), E4M3_MAX);
}

__device__ __forceinline__ float redpart64(const float* __restrict__ p, int tid) {
  float v = p[tid & 63];
  #pragma unroll
  for (int o = 32; o > 0; o >>= 1) v = fmaxf(v, __shfl_xor(v, o));
  return v;
}

// ---- prep1: bid<384 -> amax partial maxes; else cvt fp32->bf16.
__global__ __launch_bounds__(256) void prep1(const float* __restrict__ W0,
                                             const float* __restrict__ W1,
                                             const float* __restrict__ W2,
                                             const float* __restrict__ b0,
                                             const float* __restrict__ b1,
                                             const float* __restrict__ b2,
                                             const float* __restrict__ Xq,
                                             const float* __restrict__ Xk,
                                             const float* __restrict__ Xv,
                                             float* __restrict__ amaxpart,
                                             ushort* __restrict__ xq,
                                             ushort* __restrict__ xk,
                                             ushort* __restrict__ xv) {
  __shared__ float wred[4];
  int bid = blockIdx.x, tid = threadIdx.x;
  if (bid < 384) {
    int y = bid >> 6, xb = bid & 63;
    const float* src = (y == 0) ? W0 : (y == 1) ? W1 : (y == 2) ? W2
                     : (y == 3) ? b0 : (y == 4) ? b1 : b2;
    int n = (y < 3) ? 1048576 : 1024;
    float m = 0.0f;
    for (int i = xb * 256 + tid; i < n; i += 64 * 256)
      m = fmaxf(m, fabsf(src[i]));
    #pragma unroll
    for (int off = 32; off > 0; off >>= 1)
      m = fmaxf(m, __shfl_xor(m, off));
    if ((tid & 63) == 0) wred[tid >> 6] = m;
    __syncthreads();
    if (tid == 0)
      amaxpart[y * 64 + xb] = fmaxf(fmaxf(wred[0], wred[1]), fmaxf(wred[2], wred[3]));
  } else {
    int t = bid - 384;
    int y = t >> 12, xb = t & 4095;
    const float* in = (y == 0) ? Xq : (y == 1) ? Xk : Xv;
    ushort* out = (y == 0) ? xq : (y == 1) ? xk : xv;
    int i = xb * 256 + tid;
    f4 v = *(const f4*)(in + (size_t)i * 4);
    uint2 o;
    o.x = (unsigned)f2bf(v[0]) | ((unsigned)f2bf(v[1]) << 16);
    o.y = (unsigned)f2bf(v[2]) | ((unsigned)f2bf(v[3]) << 16);
    *(uint2*)(out + (size_t)i * 4) = o;
  }
}

// ---- prep2: bid<768 repack W->Bt; bid<780 qvec bias; else wo_trans.
__global__ __launch_bounds__(256) void prep2(const float* __restrict__ W0,
                                             const float* __restrict__ W1,
                                             const float* __restrict__ W2,
                                             const float* __restrict__ WO,
                                             const float* __restrict__ b0,
                                             const float* __restrict__ b1,
                                             const float* __restrict__ b2,
                                             const float* __restrict__ amaxpart,
                                             float* __restrict__ amax,
                                             ushort* __restrict__ o0,
                                             ushort* __restrict__ o1,
                                             ushort* __restrict__ o2,
                                             ushort* __restrict__ woT,
                                             float* __restrict__ bq,
                                             float* __restrict__ bk,
                                             float* __restrict__ bv) {
  __shared__ float tile[64][65];
  int bid = blockIdx.x, tid = threadIdx.x;
  if (bid < 768) {
    int z = bid >> 8, r = bid & 255, hh = r >> 4, xb = r & 15;
    const float* W = (z == 0) ? W0 : (z == 1) ? W1 : W2;
    ushort* Bt = (z == 0) ? o0 : (z == 1) ? o1 : o2;
    float am = redpart64(amaxpart + z * 64, tid);
    if (r == 0 && tid == 0) amax[z] = am;
    int d0 = xb * 64;
    int e = tid & 63, dd = tid >> 6;
    #pragma unroll
    for (int p = 0; p < 16; p++)
      tile[dd + p * 4][e] = W[(size_t)hh * 65536 + (size_t)(d0 + dd + p * 4) * 64 + e];
    __syncthreads();
    int d = tid & 63, ee = tid >> 6;
    #pragma unroll
    for (int p = 0; p < 16; p++) {
      int e2 = ee + p * 4;
      Bt[(size_t)(hh * 64 + e2) * 1024 + d0 + d] = f2bf(qdq_qval(tile[d][e2], am));
    }
  } else if (bid < 780) {
    int q = bid - 768, y = q >> 2, xb = q & 3;
    const float* b = (y == 0) ? b0 : (y == 1) ? b1 : b2;
    float* o = (y == 0) ? bq : (y == 1) ? bk : bv;
    float am = redpart64(amaxpart + (3 + y) * 64, tid);
    int idx = xb * 256 + tid;
    if (idx < 1024) {
      float qv = qdq_qval(b[idx], am);
      o[idx] = qv * (fmaxf(am, 1e-12f) * (1.0f / E4M3_MAX));
    }
  } else {
    int t = bid - 780;
    int xb = t & 15, yb = t >> 4;
    int d0 = xb * 64, he0 = yb * 64;
    int dcol = tid & 63, hr = tid >> 6;
    #pragma unroll
    for (int p = 0; p < 16; p++)
      tile[hr + p * 4][dcol] = WO[(size_t)(he0 + hr + p * 4) * 1024 + d0 + dcol];
    __syncthreads();
    int hcol = tid & 63, dr = tid >> 6;
    #pragma unroll
    for (int p = 0; p < 16; p++)
      woT[(size_t)(d0 + dr + p * 4) * 1024 + he0 + hcol] = f2bf(tile[hcol][dr + p * 4]);
  }
}

// GEMM body (gemm3 only): tile 128x128, BK=32, DOUBLE-BUFFERED staging
// (r18-verified: gemm3 <=44.6us). MODE 2: rotary epilogue (q/k).
// MODE 3: V-transpose epilogue (As reused as 128*136 buf).
template <int MODE>
__device__ __forceinline__ void gemm_body(const ushort* __restrict__ A,
                                          const ushort* __restrict__ Bt,
                                          const float* __restrict__ bias, float s_inv,
                                          ushort* __restrict__ outb,
                                          int bx, int by, ushort* As, ushort* Bs) {
  const int K = 1024, N = 1024, JF = 4;
  const int ABUF = 4096, BBUF = 4096;
  int tid = threadIdx.x;
  int w = tid >> 6, lane = tid & 63, quad = lane >> 4, l16 = lane & 15;
  int wm = w & 1, wn = w >> 1;
  int row0 = by * 128, col0 = bx * 128;
  f32x4 acc[4][4] = {};

  {                                       // prologue: stage k0=0 into buf0
    int u = tid;
    gll16(&A[(size_t)(row0 + (u >> 2)) * K + (u & 3) * 8], &As[u * 8]);
    u = tid + 256;
    gll16(&A[(size_t)(row0 + (u >> 2)) * K + (u & 3) * 8], &As[u * 8]);
    u = tid;
    gll16(&Bt[(size_t)(col0 + (u >> 2)) * K + (u & 3) * 8], &Bs[u * 8]);
    u = tid + 256;
    gll16(&Bt[(size_t)(col0 + (u >> 2)) * K + (u & 3) * 8], &Bs[u * 8]);
  }

  for (int t = 0; t < 32; t++) {
    const int cur = t & 1;
    __syncthreads();                      // drains prefetch for cur buf
    if (t + 1 < 32) {                     // prefetch t+1 into buf^1
      const int nb = cur ^ 1;
      int k0 = (t + 1) * 32;
      int u = tid;
      gll16(&A[(size_t)(row0 + (u >> 2)) * K + k0 + (u & 3) * 8], &As[nb * ABUF + u * 8]);
      u = tid + 256;
      gll16(&A[(size_t)(row0 + (u >> 2)) * K + k0 + (u & 3) * 8], &As[nb * ABUF + u * 8]);
      u = tid;
      gll16(&Bt[(size_t)(col0 + (u >> 2)) * K + k0 + (u & 3) * 8], &Bs[nb * BBUF + u * 8]);
      u = tid + 256;
      gll16(&Bt[(size_t)(col0 + (u >> 2)) * K + k0 + (u & 3) * 8], &Bs[nb * BBUF + u * 8]);
    }
    const ushort* Ac = As + cur * ABUF;
    const ushort* Bc = Bs + cur * BBUF;
    bf16x8 af[4], bfr[JF];
    #pragma unroll
    for (int i = 0; i < 4; i++)
      af[i] = *(const bf16x8*)&Ac[(wm * 64 + i * 16 + l16) * 32 + quad * 8];
    #pragma unroll
    for (int j = 0; j < JF; j++)
      bfr[j] = *(const bf16x8*)&Bc[(wn * 64 + j * 16 + l16) * 32 + quad * 8];
    #pragma unroll
    for (int i = 0; i < 4; i++)
      #pragma unroll
      for (int j = 0; j < JF; j++)
        acc[i][j] = __builtin_amdgcn_mfma_f32_16x16x32_bf16(af[i], bfr[j], acc[i][j], 0, 0, 0);
  }

  if (MODE == 2) {
    float bv0[4];
    #pragma unroll
    for (int j = 0; j < 4; j++) bv0[j] = bias[col0 + wn * 64 + j * 16 + l16];
    #pragma unroll
    for (int jp = 0; jp < 2; jp++) {
      float invf = exp2f((float)(jp * 16 + l16) * (-13.287712379549449f / 32.0f));
      int collo = col0 + wn * 64 + jp * 16 + l16;
      #pragma unroll
      for (int i = 0; i < 4; i++) {
        #pragma unroll
        for (int r = 0; r < 4; r++) {
          int row = row0 + wm * 64 + i * 16 + quad * 4 + r;
          float ang = (float)(row & 2047) * invf;
          float sn = __sinf(ang), c = __cosf(ang);
          float lo = acc[i][jp][r] * s_inv + bv0[jp];
          float hi = acc[i][jp + 2][r] * s_inv + bv0[jp + 2];
          outb[(size_t)row * N + collo] = f2bf(lo * c - hi * sn);
          outb[(size_t)row * N + collo + 32] = f2bf(hi * c + lo * sn);
        }
      }
    }
  } else {
    __syncthreads();
    ushort* sb = As;                      // 128 x 136 ushorts
    #pragma unroll
    for (int j = 0; j < JF; j++) {
      int colL = wn * 64 + j * 16 + l16;
      float bv = bias[col0 + colL];
      #pragma unroll
      for (int i = 0; i < 4; i++) {
        int rowL = wm * 64 + i * 16 + quad * 4;
        uint2 o;
        o.x = (unsigned)f2bf(acc[i][j][0] * s_inv + bv) |
              ((unsigned)f2bf(acc[i][j][1] * s_inv + bv) << 16);
        o.y = (unsigned)f2bf(acc[i][j][2] * s_inv + bv) |
              ((unsigned)f2bf(acc[i][j][3] * s_inv + bv) << 16);
        *(uint2*)&sb[colL * 136 + rowL] = o;
      }
    }
    __syncthreads();
    int bb = row0 >> 11, sloc = row0 & 2047;
    #pragma unroll
    for (int p = 0; p < 8; p++) {
      int u = tid + p * 256;
      int r = u >> 4, cc = u & 15;
      *(uint4*)&outb[(size_t)(bb * 1024 + col0 + r) * 2048 + sloc + cc * 8] =
          *(const uint4*)&sb[r * 136 + cc * 8];
    }
  }
}

// Batched QKV projection: 1D grid 768, XCD-remapped.
__global__ __launch_bounds__(256) void gemm3_qkv(const ushort* __restrict__ xq,
                                                 const ushort* __restrict__ xk,
                                                 const ushort* __restrict__ xv,
                                                 const ushort* __restrict__ wq,
                                                 const ushort* __restrict__ wk,
                                                 const ushort* __restrict__ wv,
                                                 const float* __restrict__ bq,
                                                 const float* __restrict__ bk,
                                                 const float* __restrict__ bv,
                                                 const float* __restrict__ amax,
                                                 ushort* __restrict__ oq,
                                                 ushort* __restrict__ ok,
                                                 ushort* __restrict__ vT) {
  __shared__ __align__(16) ushort sb[17408];   // As dbuf 2x4096 | Bs dbuf 2x4096
  ushort* As = sb;
  ushort* Bs = sb + 8192;
  int bid = blockIdx.x;
  int rr = bid & 7, t = bid >> 3;
  int bx = t & 7, gq = rr + 8 * (t >> 3);
  int by = gq & 31, z = gq >> 5;
  const ushort* A  = (z == 0) ? xq : (z == 1) ? xk : xv;
  const ushort* Bt = (z == 0) ? wq : (z == 1) ? wk : wv;
  const float* bias = (z == 0) ? bq : (z == 1) ? bk : bv;
  float s_inv = fmaxf(amax[z], 1e-12f) * (1.0f / E4M3_MAX);
  if (z == 2)
    gemm_body<3>(A, Bt, bias, s_inv, vT, bx, by, As, Bs);
  else
    gemm_body<2>(A, Bt, bias, s_inv, (z == 0) ? oq : ok, bx, by, As, Bs);
}

// Output projection (r17-verified body): 128x64 tile, BK=64 + XOR swizzle,
// 1D grid 512, XCD-remapped.
__global__ __launch_bounds__(256) void gemm_wo(const ushort* __restrict__ A,
                                               const ushort* __restrict__ Bt,
                                               const float* __restrict__ bias,
                                               float* __restrict__ out) {
  __shared__ __align__(16) ushort As[8192], Bs[4096];
  int bid = blockIdx.x;
  int rr = bid & 7, tt = bid >> 3;
  int bx = tt & 15, by = rr + 8 * (tt >> 4);
  const int K = 1024, N = 1024;
  int tid = threadIdx.x;
  int w = tid >> 6, lane = tid & 63, quad = lane >> 4, l16 = lane & 15;
  int wm = w & 1, wn = w >> 1;
  int row0 = by * 128, col0 = bx * 64;
  f32x4 acc[4][2] = {};

  for (int k0 = 0; k0 < K; k0 += 64) {
    __syncthreads();
    #pragma unroll
    for (int p = 0; p < 4; p++) {
      int u = tid + p * 256;
      int r = u >> 3, c = u & 7, cs = c ^ (r & 7);
      gll16(&A[(size_t)(row0 + r) * K + k0 + cs * 8], &As[u * 8]);
    }
    #pragma unroll
    for (int p = 0; p < 2; p++) {
      int u = tid + p * 256;
      int r = u >> 3, c = u & 7, cs = c ^ (r & 7);
      gll16(&Bt[(size_t)(col0 + r) * K + k0 + cs * 8], &Bs[u * 8]);
    }
    __syncthreads();
    #pragma unroll
    for (int kk = 0; kk < 2; kk++) {
      bf16x8 af[4], bfr[2];
      #pragma unroll
      for (int i = 0; i < 4; i++) {
        int arow = wm * 64 + i * 16 + l16;
        af[i] = *(const bf16x8*)&As[arow * 64 + (((kk * 4 + quad) ^ (arow & 7)) * 8)];
      }
      #pragma unroll
      for (int j = 0; j < 2; j++) {
        int brow = wn * 32 + j * 16 + l16;
        bfr[j] = *(const bf16x8*)&Bs[brow * 64 + (((kk * 4 + quad) ^ (brow & 7)) * 8)];
      }
      #pragma unroll
      for (int i = 0; i < 4; i++)
        #pragma unroll
        for (int j = 0; j < 2; j++)
          acc[i][j] = __builtin_amdgcn_mfma_f32_16x16x32_bf16(af[i], bfr[j], acc[i][j], 0, 0, 0);
    }
  }

  #pragma unroll
  for (int j = 0; j < 2; j++) {
    int col = col0 + wn * 32 + j * 16 + l16;
    float bv = bias[col];
    #pragma unroll
    for (int i = 0; i < 4; i++) {
      int row = row0 + wm * 64 + i * 16 + quad * 4;
      #pragma unroll
      for (int r = 0; r < 4; r++)
        out[(size_t)(row + r) * N + col] = acc[i][j][r] + bv;
    }
  }
}

// ---- Flash v9 (r17 VERBATIM: balanced 2-blocks/CU + setprio). ----
__global__ __launch_bounds__(512, 4) void flash_mfma9(const ushort* __restrict__ qb,
                                                      const ushort* __restrict__ kb,
                                                      const ushort* __restrict__ vT,
                                                      ushort* __restrict__ zb) {
  int h = blockIdx.y, b = blockIdx.z;
  int tid = threadIdx.x;
  int w8 = tid >> 6;
  int g = w8 >> 2;
  int w = w8 & 3;
  int lane = tid & 63, h2 = lane >> 5, l31 = lane & 31;
  __shared__ ushort sbuf[16384 + 18432];
  ushort* Ks = sbuf + g * 4096;
  ushort* Vs = sbuf + 8192 + g * 4096;
  ushort* P2 = sbuf + 16384 + g * 9216;

  const int qrow = w * 32 + l31;
  const float CE = 0.125f;

  const int ts = tid & 255;
  const int u0 = ts, u1 = ts + 256;
  const int r0 = u0 >> 3, c0 = u0 & 7, r1 = u1 >> 3, c1 = u1 & 7;
  const int sw0 = (c0 ^ (r0 & 7)) * 8, sw1 = (c1 ^ (r1 & 7)) * 8;

  const int qt = (blockIdx.z == 0) ? (int)blockIdx.x : 15 - (int)blockIdx.x;
  const int q0 = qt * 128;
  const int qg = q0 + w * 32 + l31;
  size_t qbase = ((size_t)(b * 2048 + qg)) * 1024 + (size_t)h * 64;
  bf16x8 qf[4];
  #pragma unroll
  for (int ck = 0; ck < 4; ck++)
    qf[ck] = *(const bf16x8*)&qb[qbase + ck * 16 + h2 * 8];

  f32x16 accO[2] = {};
  float mrun = -INFINITY, lrun = 0.0f;

  const int nt = qt + 1;
  const int kt0 = g * nt;

  const ushort* ksrc0 = kb + ((size_t)(b * 2048 + kt0 * 64 + r0)) * 1024 + (size_t)h * 64 + c0 * 8;
  const ushort* ksrc1 = kb + ((size_t)(b * 2048 + kt0 * 64 + r1)) * 1024 + (size_t)h * 64 + c1 * 8;
  const ushort* vsrc0 = vT + ((size_t)((b * 16 + h) * 64 + r0)) * 2048 + kt0 * 64 + c0 * 8;
  const ushort* vsrc1 = vT + ((size_t)((b * 16 + h) * 64 + r1)) * 2048 + kt0 * 64 + c1 * 8;

  uint4 kc0 = *(const uint4*)ksrc0;
  uint4 kc1 = *(const uint4*)ksrc1;
  uint4 vc0 = *(const uint4*)vsrc0;
  uint4 vc1 = *(const uint4*)vsrc1;

  for (int t = 0; t < nt; t++) {
    int kt = kt0 + t;
    __syncthreads();
    *(uint4*)&Ks[r0 * 64 + sw0] = kc0;
    *(uint4*)&Ks[r1 * 64 + sw1] = kc1;
    *(uint4*)&Vs[r0 * 64 + sw0] = vc0;
    *(uint4*)&Vs[r1 * 64 + sw1] = vc1;
    __syncthreads();
    if (t + 1 < nt) {
      kc0 = *(const uint4*)(ksrc0 + (size_t)(t + 1) * 65536);
      kc1 = *(const uint4*)(ksrc1 + (size_t)(t + 1) * 65536);
      vc0 = *(const uint4*)(vsrc0 + (t + 1) * 64);
      vc1 = *(const uint4*)(vsrc1 + (t + 1) * 64);
    }

    bool active = (kt * 64 <= q0 + w * 32 + 31);
    if (active) {
      f32x16 sc[2] = {};
      __builtin_amdgcn_s_setprio(1);
      #pragma unroll
      for (int mf = 0; mf < 2; mf++) {
        int row = mf * 32 + l31;
        int s8 = row & 7;
        #pragma unroll
        for (int ck = 0; ck < 4; ck++) {
          bf16x8 ka = *(const bf16x8*)&Ks[row * 64 + (((2 * ck + h2) ^ s8) * 8)];
          sc[mf] = __builtin_amdgcn_mfma_f32_32x32x16_bf16(ka, qf[ck], sc[mf], 0, 0, 0);
        }
      }
      __builtin_amdgcn_s_setprio(0);

      if (kt * 64 + 63 > q0 + w * 32) {
        #pragma unroll
        for (int mf = 0; mf < 2; mf++)
          #pragma unroll
          for (int i = 0; i < 16; i++) {
            int kv = kt * 64 + mf * 32 + (i & 3) + 8 * (i >> 2) + 4 * h2;
            sc[mf][i] = (kv > qg) ? -8000.0f : sc[mf][i];
          }
      }

      float tm = sc[0][0];
      #pragma unroll
      for (int i = 1; i < 16; i++) tm = fmaxf(tm, sc[0][i]);
      #pragma unroll
      for (int i = 0; i < 16; i++) tm = fmaxf(tm, sc[1][i]);
      tm = fmaxf(tm, __shfl_xor(tm, 32));
      float mnew = fmaxf(mrun, tm);
      float alpha = __expf((mrun - mnew) * CE);
      float p[2][16];
      float rs = 0.0f;
      #pragma unroll
      for (int mf = 0; mf < 2; mf++)
        #pragma unroll
        for (int i = 0; i < 16; i++) {
          float pv = __expf((sc[mf][i] - mnew) * CE);
          p[mf][i] = pv;
          rs += pv;
        }
      rs += __shfl_xor(rs, 32);
      lrun = lrun * alpha + rs;
      mrun = mnew;
      #pragma unroll
      for (int mf = 0; mf < 2; mf++)
        #pragma unroll
        for (int i = 0; i < 16; i++) accO[mf][i] *= alpha;

      #pragma unroll
      for (int mf = 0; mf < 2; mf++)
        #pragma unroll
        for (int m = 0; m < 4; m++) {
          uint2 w2;
          w2.x = pack2bf(p[mf][4 * m + 0], p[mf][4 * m + 1]);
          w2.y = pack2bf(p[mf][4 * m + 2], p[mf][4 * m + 3]);
          *(uint2*)&P2[qrow * 72 + 32 * mf + 8 * m + 4 * h2] = w2;
        }

      __builtin_amdgcn_s_setprio(1);
      #pragma unroll
      for (int ck = 0; ck < 4; ck++) {
        bf16x8 pB = *(const bf16x8*)&P2[qrow * 72 + ck * 16 + h2 * 8];
        #pragma unroll
        for (int mf = 0; mf < 2; mf++) {
          int row = mf * 32 + l31;
          bf16x8 va = *(const bf16x8*)&Vs[row * 64 + (((2 * ck + h2) ^ (row & 7)) * 8)];
          accO[mf] = __builtin_amdgcn_mfma_f32_32x32x16_bf16(va, pB, accO[mf], 0, 0, 0);
        }
      }
      __builtin_amdgcn_s_setprio(0);
    }
  }

  __syncthreads();
  float* mbuf = (float*)sbuf;
  int midx = (w * 64 + lane) * 35;
  if (g == 1) {
    #pragma unroll
    for (int i = 0; i < 16; i++) mbuf[midx + i] = accO[0][i];
    #pragma unroll
    for (int i = 0; i < 16; i++) mbuf[midx + 16 + i] = accO[1][i];
    mbuf[midx + 32] = mrun;
    mbuf[midx + 33] = lrun;
  }
  __syncthreads();
  ushort* Osb = sbuf + 16384 + 9216;
  if (g == 0) {
    float m1 = mbuf[midx + 32], l1 = mbuf[midx + 33];
    float mn = fmaxf(mrun, m1);
    float a0 = __expf((mrun - mn) * CE), a1 = __expf((m1 - mn) * CE);
    float linv = 1.0f / (lrun * a0 + l1 * a1);
    #pragma unroll
    for (int mf = 0; mf < 2; mf++)
      #pragma unroll
      for (int m = 0; m < 4; m++) {
        int e0 = 32 * mf + 8 * m + 4 * h2;
        float o0 = (accO[mf][4 * m + 0] * a0 + mbuf[midx + 16 * mf + 4 * m + 0] * a1) * linv;
        float o1 = (accO[mf][4 * m + 1] * a0 + mbuf[midx + 16 * mf + 4 * m + 1] * a1) * linv;
        float o2 = (accO[mf][4 * m + 2] * a0 + mbuf[midx + 16 * mf + 4 * m + 2] * a1) * linv;
        float o3 = (accO[mf][4 * m + 3] * a0 + mbuf[midx + 16 * mf + 4 * m + 3] * a1) * linv;
        *(unsigned*)&Osb[qrow * 72 + e0] = pack2bf(o0, o1);
        *(unsigned*)&Osb[qrow * 72 + e0 + 2] = pack2bf(o2, o3);
      }
  }
  __syncthreads();
  size_t obase = ((size_t)(b * 2048 + q0)) * 1024 + (size_t)h * 64;
  #pragma unroll
  for (int i = 0; i < 2; i++) {
    int u = tid + i * 512;
    int r = u >> 3, blk = u & 7;
    *(uint4*)&zb[obase + (size_t)r * 1024 + blk * 8] = *(const uint4*)&Osb[r * 72 + blk * 8];
  }
}

extern "C" void kernel_launch(void* const* d_in, const int* in_sizes, int n_in,
                              void* d_out, int out_size, void* d_ws, size_t ws_size,
                              hipStream_t stream) {
  const float* Xq  = (const float*)d_in[0];
  const float* Xk  = (const float*)d_in[1];
  const float* Xv  = (const float*)d_in[2];
  const float* W_Q = (const float*)d_in[3];
  const float* W_K = (const float*)d_in[4];
  const float* W_V = (const float*)d_in[5];
  const float* W_O = (const float*)d_in[6];
  const float* b_Q = (const float*)d_in[7];
  const float* b_K = (const float*)d_in[8];
  const float* b_V = (const float*)d_in[9];
  const float* b_O = (const float*)d_in[10];
  float* out = (float*)d_out;

  char* base = (char*)d_ws;
  float*  amax = (float*)(base + 0);
  float*  amaxpart = (float*)(base + 1024);
  float*  bq   = (float*)(base + 4096);
  float*  bk   = (float*)(base + 8192);
  float*  bv   = (float*)(base + 12288);
  ushort* wq   = (ushort*)(base + 16384);
  ushort* wk   = (ushort*)(base + 16384 + 2097152);
  ushort* wv   = (ushort*)(base + 16384 + 2u * 2097152);
  ushort* woT  = (ushort*)(base + 16384 + 3u * 2097152);
  ushort* xq   = (ushort*)(base + 8404992);
  ushort* xk   = (ushort*)(base + 16793600);
  ushort* xv   = (ushort*)(base + 25182208);
  ushort* qbf  = (ushort*)(base + 33570816);
  ushort* kbf  = (ushort*)(base + 41959424);
  ushort* vT   = (ushort*)(base + 50348032);
  ushort* zbf  = xk;   // xk dead after gemm3_qkv

  prep1<<<12672, 256, 0, stream>>>(W_Q, W_K, W_V, b_Q, b_K, b_V, Xq, Xk, Xv,
                                   amaxpart, xq, xk, xv);
  prep2<<<1036, 256, 0, stream>>>(W_Q, W_K, W_V, W_O, b_Q, b_K, b_V,
                                  amaxpart, amax, wq, wk, wv, woT, bq, bk, bv);
  gemm3_qkv<<<768, 256, 0, stream>>>(xq, xk, xv, wq, wk, wv, bq, bk, bv, amax,
                                     qbf, kbf, vT);
  dim3 fgrid(16, 16, 2);
  flash_mfma9<<<fgrid, 512, 0, stream>>>(qbf, kbf, vT, zbf);
  gemm_wo<<<512, 256, 0, stream>>>(zbf, woT, b_O, out);
}

// Round 15
// 222.415 us; speedup vs baseline: 1.0549x; 1.0268x over previous
//
#include <hip/hip_runtime.h>
#include <math.h>

// QuantizedAttention: B=2, S=2048, D=1024, H=16, Dh=64.
// Round 20:
//  - POST-MORTEM r19: BK32-dbuf gemm3 reads are 8-WAY bank-conflicted
//    (3.24M counted): row-stride 64B -> bank-group (4row+quad)%8 collapses
//    to row parity. r18's "<44.6" was codegen luck (rule #19).
//  - FIX: pair-XOR chunk swizzle for BK32 (4 chunks/row): stage global
//    chunk c^((r>>1)&3) into linear LDS; read chunk quad^((row>>1)&3).
//    Bank-group = (4row + quad^((row>>1)&3))%8 -> rows 0-7 cover all 8
//    groups, 2 lanes/group = free. Same involution discipline as the
//    r14-verified BK64 fix. Staging pointers hoisted (uniform k0 offset)
//    to cut the 40% VALUBusy address recompute.
//  - gemm_wo (r17 BK64+swizzle body), flash (r17 mfma9+setprio), preps,
//    XCD remaps: byte-identical to r19.

typedef __attribute__((ext_vector_type(8))) short bf16x8;
typedef __attribute__((ext_vector_type(16))) float f32x16;
typedef __attribute__((ext_vector_type(4))) float f32x4;
typedef __attribute__((ext_vector_type(4))) float f4;

#define E4M3_MAX 448.0f

__device__ inline float bf2f(ushort u) { return __uint_as_float(((unsigned)u) << 16); }
__device__ inline ushort f2bf(float f) {
  unsigned u = __float_as_uint(f);
  return (ushort)((u + 0x7FFF + ((u >> 16) & 1)) >> 16);  // RNE
}
__device__ inline unsigned pack2bf(float a, float b) {
  unsigned ua = __float_as_uint(a), ub = __float_as_uint(b);
  return ((ua + 0x8000u) >> 16) | ((ub + 0x8000u) & 0xFFFF0000u);
}

__device__ __forceinline__ void gll16(const ushort* g, ushort* l) {
  __builtin_amdgcn_global_load_lds(
      (const __attribute__((address_space(1))) unsigned int*)g,
      (__attribute__((address_space(3))) unsigned int*)l, 16, 0, 0);
}

__device__ inline float qdq_qval(float w, float amax) {
  float scale = E4M3_MAX / fmaxf(amax, 1e-12f);
  float v = w * scale;
  float a = fmaxf(fabsf(v), 1e-30f);
  int ex;
  (void)frexpf(a, &ex);
  float e = fminf(fmaxf((float)(ex - 1), -6.0f), 8.0f);
  float step = exp2f(e - 3.0f);
  float q = rintf(v / step) * step;
  return fminf(fmaxf(q, -E4M3_MAX), E4M3_MAX);
}

__device__ __forceinline__ float redpart64(const float* __restrict__ p, int tid) {
  float v = p[tid & 63];
  #pragma unroll
  for (int o = 32; o > 0; o >>= 1) v = fmaxf(v, __shfl_xor(v, o));
  return v;
}

// ---- prep1: bid<384 -> amax partial maxes; else cvt fp32->bf16.
__global__ __launch_bounds__(256) void prep1(const float* __restrict__ W0,
                                             const float* __restrict__ W1,
                                             const float* __restrict__ W2,
                                             const float* __restrict__ b0,
                                             const float* __restrict__ b1,
                                             const float* __restrict__ b2,
                                             const float* __restrict__ Xq,
                                             const float* __restrict__ Xk,
                                             const float* __restrict__ Xv,
                                             float* __restrict__ amaxpart,
                                             ushort* __restrict__ xq,
                                             ushort* __restrict__ xk,
                                             ushort* __restrict__ xv) {
  __shared__ float wred[4];
  int bid = blockIdx.x, tid = threadIdx.x;
  if (bid < 384) {
    int y = bid >> 6, xb = bid & 63;
    const float* src = (y == 0) ? W0 : (y == 1) ? W1 : (y == 2) ? W2
                     : (y == 3) ? b0 : (y == 4) ? b1 : b2;
    int n = (y < 3) ? 1048576 : 1024;
    float m = 0.0f;
    for (int i = xb * 256 + tid; i < n; i += 64 * 256)
      m = fmaxf(m, fabsf(src[i]));
    #pragma unroll
    for (int off = 32; off > 0; off >>= 1)
      m = fmaxf(m, __shfl_xor(m, off));
    if ((tid & 63) == 0) wred[tid >> 6] = m;
    __syncthreads();
    if (tid == 0)
      amaxpart[y * 64 + xb] = fmaxf(fmaxf(wred[0], wred[1]), fmaxf(wred[2], wred[3]));
  } else {
    int t = bid - 384;
    int y = t >> 12, xb = t & 4095;
    const float* in = (y == 0) ? Xq : (y == 1) ? Xk : Xv;
    ushort* out = (y == 0) ? xq : (y == 1) ? xk : xv;
    int i = xb * 256 + tid;
    f4 v = *(const f4*)(in + (size_t)i * 4);
    uint2 o;
    o.x = (unsigned)f2bf(v[0]) | ((unsigned)f2bf(v[1]) << 16);
    o.y = (unsigned)f2bf(v[2]) | ((unsigned)f2bf(v[3]) << 16);
    *(uint2*)(out + (size_t)i * 4) = o;
  }
}

// ---- prep2: bid<768 repack W->Bt; bid<780 qvec bias; else wo_trans.
__global__ __launch_bounds__(256) void prep2(const float* __restrict__ W0,
                                             const float* __restrict__ W1,
                                             const float* __restrict__ W2,
                                             const float* __restrict__ WO,
                                             const float* __restrict__ b0,
                                             const float* __restrict__ b1,
                                             const float* __restrict__ b2,
                                             const float* __restrict__ amaxpart,
                                             float* __restrict__ amax,
                                             ushort* __restrict__ o0,
                                             ushort* __restrict__ o1,
                                             ushort* __restrict__ o2,
                                             ushort* __restrict__ woT,
                                             float* __restrict__ bq,
                                             float* __restrict__ bk,
                                             float* __restrict__ bv) {
  __shared__ float tile[64][65];
  int bid = blockIdx.x, tid = threadIdx.x;
  if (bid < 768) {
    int z = bid >> 8, r = bid & 255, hh = r >> 4, xb = r & 15;
    const float* W = (z == 0) ? W0 : (z == 1) ? W1 : W2;
    ushort* Bt = (z == 0) ? o0 : (z == 1) ? o1 : o2;
    float am = redpart64(amaxpart + z * 64, tid);
    if (r == 0 && tid == 0) amax[z] = am;
    int d0 = xb * 64;
    int e = tid & 63, dd = tid >> 6;
    #pragma unroll
    for (int p = 0; p < 16; p++)
      tile[dd + p * 4][e] = W[(size_t)hh * 65536 + (size_t)(d0 + dd + p * 4) * 64 + e];
    __syncthreads();
    int d = tid & 63, ee = tid >> 6;
    #pragma unroll
    for (int p = 0; p < 16; p++) {
      int e2 = ee + p * 4;
      Bt[(size_t)(hh * 64 + e2) * 1024 + d0 + d] = f2bf(qdq_qval(tile[d][e2], am));
    }
  } else if (bid < 780) {
    int q = bid - 768, y = q >> 2, xb = q & 3;
    const float* b = (y == 0) ? b0 : (y == 1) ? b1 : b2;
    float* o = (y == 0) ? bq : (y == 1) ? bk : bv;
    float am = redpart64(amaxpart + (3 + y) * 64, tid);
    int idx = xb * 256 + tid;
    if (idx < 1024) {
      float qv = qdq_qval(b[idx], am);
      o[idx] = qv * (fmaxf(am, 1e-12f) * (1.0f / E4M3_MAX));
    }
  } else {
    int t = bid - 780;
    int xb = t & 15, yb = t >> 4;
    int d0 = xb * 64, he0 = yb * 64;
    int dcol = tid & 63, hr = tid >> 6;
    #pragma unroll
    for (int p = 0; p < 16; p++)
      tile[hr + p * 4][dcol] = WO[(size_t)(he0 + hr + p * 4) * 1024 + d0 + dcol];
    __syncthreads();
    int hcol = tid & 63, dr = tid >> 6;
    #pragma unroll
    for (int p = 0; p < 16; p++)
      woT[(size_t)(d0 + dr + p * 4) * 1024 + he0 + hcol] = f2bf(tile[hcol][dr + p * 4]);
  }
}

// GEMM body (gemm3 only): tile 128x128, BK=32, DOUBLE-BUFFERED staging with
// pair-XOR chunk swizzle: stage global chunk c^((r>>1)&3) into linear LDS
// unit (r,c); read chunk quad^((row>>1)&3). Bank-group (4row+swq)%8 covers
// all 8 groups over rows 0-7 -> 2 lanes/group (free). Staging pointers
// hoisted; prefetch offset is uniform k0.
// MODE 2: rotary epilogue (q/k). MODE 3: V-transpose epilogue.
template <int MODE>
__device__ __forceinline__ void gemm_body(const ushort* __restrict__ A,
                                          const ushort* __restrict__ Bt,
                                          const float* __restrict__ bias, float s_inv,
                                          ushort* __restrict__ outb,
                                          int bx, int by, ushort* As, ushort* Bs) {
  const int K = 1024, N = 1024, JF = 4;
  const int ABUF = 4096, BBUF = 4096;
  int tid = threadIdx.x;
  int w = tid >> 6, lane = tid & 63, quad = lane >> 4, l16 = lane & 15;
  int wm = w & 1, wn = w >> 1;
  int row0 = by * 128, col0 = bx * 128;
  f32x4 acc[4][4] = {};

  // hoisted staging pointers (unit u -> row r=u>>2, swizzled chunk)
  const int u0 = tid, u1 = tid + 256;
  const int ar0 = u0 >> 2, ac0 = ((u0 & 3) ^ ((ar0 >> 1) & 3)) * 8;
  const int ar1 = u1 >> 2, ac1 = ((u1 & 3) ^ ((ar1 >> 1) & 3)) * 8;
  const ushort* pa0 = A + (size_t)(row0 + ar0) * K + ac0;
  const ushort* pa1 = A + (size_t)(row0 + ar1) * K + ac1;
  const ushort* pb0 = Bt + (size_t)(col0 + ar0) * K + ac0;
  const ushort* pb1 = Bt + (size_t)(col0 + ar1) * K + ac1;

  {                                       // prologue: stage k0=0 into buf0
    gll16(pa0, &As[u0 * 8]);
    gll16(pa1, &As[u1 * 8]);
    gll16(pb0, &Bs[u0 * 8]);
    gll16(pb1, &Bs[u1 * 8]);
  }

  for (int t = 0; t < 32; t++) {
    const int cur = t & 1;
    __syncthreads();                      // drains prefetch for cur buf
    if (t + 1 < 32) {                     // prefetch t+1 into buf^1
      const int nb = cur ^ 1;
      const int k0 = (t + 1) * 32;        // uniform offset
      gll16(pa0 + k0, &As[nb * ABUF + u0 * 8]);
      gll16(pa1 + k0, &As[nb * ABUF + u1 * 8]);
      gll16(pb0 + k0, &Bs[nb * BBUF + u0 * 8]);
      gll16(pb1 + k0, &Bs[nb * BBUF + u1 * 8]);
    }
    const ushort* Ac = As + cur * ABUF;
    const ushort* Bc = Bs + cur * BBUF;
    bf16x8 af[4], bfr[JF];
    #pragma unroll
    for (int i = 0; i < 4; i++) {
      int arow = wm * 64 + i * 16 + l16;
      af[i] = *(const bf16x8*)&Ac[arow * 32 + ((quad ^ ((arow >> 1) & 3)) * 8)];
    }
    #pragma unroll
    for (int j = 0; j < JF; j++) {
      int brow = wn * 64 + j * 16 + l16;
      bfr[j] = *(const bf16x8*)&Bc[brow * 32 + ((quad ^ ((brow >> 1) & 3)) * 8)];
    }
    #pragma unroll
    for (int i = 0; i < 4; i++)
      #pragma unroll
      for (int j = 0; j < JF; j++)
        acc[i][j] = __builtin_amdgcn_mfma_f32_16x16x32_bf16(af[i], bfr[j], acc[i][j], 0, 0, 0);
  }

  if (MODE == 2) {
    float bv0[4];
    #pragma unroll
    for (int j = 0; j < 4; j++) bv0[j] = bias[col0 + wn * 64 + j * 16 + l16];
    #pragma unroll
    for (int jp = 0; jp < 2; jp++) {
      float invf = exp2f((float)(jp * 16 + l16) * (-13.287712379549449f / 32.0f));
      int collo = col0 + wn * 64 + jp * 16 + l16;
      #pragma unroll
      for (int i = 0; i < 4; i++) {
        #pragma unroll
        for (int r = 0; r < 4; r++) {
          int row = row0 + wm * 64 + i * 16 + quad * 4 + r;
          float ang = (float)(row & 2047) * invf;
          float sn = __sinf(ang), c = __cosf(ang);
          float lo = acc[i][jp][r] * s_inv + bv0[jp];
          float hi = acc[i][jp + 2][r] * s_inv + bv0[jp + 2];
          outb[(size_t)row * N + collo] = f2bf(lo * c - hi * sn);
          outb[(size_t)row * N + collo + 32] = f2bf(hi * c + lo * sn);
        }
      }
    }
  } else {
    __syncthreads();
    ushort* sb = As;                      // 128 x 136 ushorts
    #pragma unroll
    for (int j = 0; j < JF; j++) {
      int colL = wn * 64 + j * 16 + l16;
      float bv = bias[col0 + colL];
      #pragma unroll
      for (int i = 0; i < 4; i++) {
        int rowL = wm * 64 + i * 16 + quad * 4;
        uint2 o;
        o.x = (unsigned)f2bf(acc[i][j][0] * s_inv + bv) |
              ((unsigned)f2bf(acc[i][j][1] * s_inv + bv) << 16);
        o.y = (unsigned)f2bf(acc[i][j][2] * s_inv + bv) |
              ((unsigned)f2bf(acc[i][j][3] * s_inv + bv) << 16);
        *(uint2*)&sb[colL * 136 + rowL] = o;
      }
    }
    __syncthreads();
    int bb = row0 >> 11, sloc = row0 & 2047;
    #pragma unroll
    for (int p = 0; p < 8; p++) {
      int u = tid + p * 256;
      int r = u >> 4, cc = u & 15;
      *(uint4*)&outb[(size_t)(bb * 1024 + col0 + r) * 2048 + sloc + cc * 8] =
          *(const uint4*)&sb[r * 136 + cc * 8];
    }
  }
}

// Batched QKV projection: 1D grid 768, XCD-remapped.
__global__ __launch_bounds__(256) void gemm3_qkv(const ushort* __restrict__ xq,
                                                 const ushort* __restrict__ xk,
                                                 const ushort* __restrict__ xv,
                                                 const ushort* __restrict__ wq,
                                                 const ushort* __restrict__ wk,
                                                 const ushort* __restrict__ wv,
                                                 const float* __restrict__ bq,
                                                 const float* __restrict__ bk,
                                                 const float* __restrict__ bv,
                                                 const float* __restrict__ amax,
                                                 ushort* __restrict__ oq,
                                                 ushort* __restrict__ ok,
                                                 ushort* __restrict__ vT) {
  __shared__ __align__(16) ushort sb[17408];   // As dbuf 2x4096 | Bs dbuf 2x4096
  ushort* As = sb;
  ushort* Bs = sb + 8192;
  int bid = blockIdx.x;
  int rr = bid & 7, t = bid >> 3;
  int bx = t & 7, gq = rr + 8 * (t >> 3);
  int by = gq & 31, z = gq >> 5;
  const ushort* A  = (z == 0) ? xq : (z == 1) ? xk : xv;
  const ushort* Bt = (z == 0) ? wq : (z == 1) ? wk : wv;
  const float* bias = (z == 0) ? bq : (z == 1) ? bk : bv;
  float s_inv = fmaxf(amax[z], 1e-12f) * (1.0f / E4M3_MAX);
  if (z == 2)
    gemm_body<3>(A, Bt, bias, s_inv, vT, bx, by, As, Bs);
  else
    gemm_body<2>(A, Bt, bias, s_inv, (z == 0) ? oq : ok, bx, by, As, Bs);
}

// Output projection (r17-verified body): 128x64 tile, BK=64 + XOR swizzle,
// 1D grid 512, XCD-remapped.
__global__ __launch_bounds__(256) void gemm_wo(const ushort* __restrict__ A,
                                               const ushort* __restrict__ Bt,
                                               const float* __restrict__ bias,
                                               float* __restrict__ out) {
  __shared__ __align__(16) ushort As[8192], Bs[4096];
  int bid = blockIdx.x;
  int rr = bid & 7, tt = bid >> 3;
  int bx = tt & 15, by = rr + 8 * (tt >> 4);
  const int K = 1024, N = 1024;
  int tid = threadIdx.x;
  int w = tid >> 6, lane = tid & 63, quad = lane >> 4, l16 = lane & 15;
  int wm = w & 1, wn = w >> 1;
  int row0 = by * 128, col0 = bx * 64;
  f32x4 acc[4][2] = {};

  for (int k0 = 0; k0 < K; k0 += 64) {
    __syncthreads();
    #pragma unroll
    for (int p = 0; p < 4; p++) {
      int u = tid + p * 256;
      int r = u >> 3, c = u & 7, cs = c ^ (r & 7);
      gll16(&A[(size_t)(row0 + r) * K + k0 + cs * 8], &As[u * 8]);
    }
    #pragma unroll
    for (int p = 0; p < 2; p++) {
      int u = tid + p * 256;
      int r = u >> 3, c = u & 7, cs = c ^ (r & 7);
      gll16(&Bt[(size_t)(col0 + r) * K + k0 + cs * 8], &Bs[u * 8]);
    }
    __syncthreads();
    #pragma unroll
    for (int kk = 0; kk < 2; kk++) {
      bf16x8 af[4], bfr[2];
      #pragma unroll
      for (int i = 0; i < 4; i++) {
        int arow = wm * 64 + i * 16 + l16;
        af[i] = *(const bf16x8*)&As[arow * 64 + (((kk * 4 + quad) ^ (arow & 7)) * 8)];
      }
      #pragma unroll
      for (int j = 0; j < 2; j++) {
        int brow = wn * 32 + j * 16 + l16;
        bfr[j] = *(const bf16x8*)&Bs[brow * 64 + (((kk * 4 + quad) ^ (brow & 7)) * 8)];
      }
      #pragma unroll
      for (int i = 0; i < 4; i++)
        #pragma unroll
        for (int j = 0; j < 2; j++)
          acc[i][j] = __builtin_amdgcn_mfma_f32_16x16x32_bf16(af[i], bfr[j], acc[i][j], 0, 0, 0);
    }
  }

  #pragma unroll
  for (int j = 0; j < 2; j++) {
    int col = col0 + wn * 32 + j * 16 + l16;
    float bv = bias[col];
    #pragma unroll
    for (int i = 0; i < 4; i++) {
      int row = row0 + wm * 64 + i * 16 + quad * 4;
      #pragma unroll
      for (int r = 0; r < 4; r++)
        out[(size_t)(row + r) * N + col] = acc[i][j][r] + bv;
    }
  }
}

// ---- Flash v9 (r17 VERBATIM: balanced 2-blocks/CU + setprio). ----
__global__ __launch_bounds__(512, 4) void flash_mfma9(const ushort* __restrict__ qb,
                                                      const ushort* __restrict__ kb,
                                                      const ushort* __restrict__ vT,
                                                      ushort* __restrict__ zb) {
  int h = blockIdx.y, b = blockIdx.z;
  int tid = threadIdx.x;
  int w8 = tid >> 6;
  int g = w8 >> 2;
  int w = w8 & 3;
  int lane = tid & 63, h2 = lane >> 5, l31 = lane & 31;
  __shared__ ushort sbuf[16384 + 18432];
  ushort* Ks = sbuf + g * 4096;
  ushort* Vs = sbuf + 8192 + g * 4096;
  ushort* P2 = sbuf + 16384 + g * 9216;

  const int qrow = w * 32 + l31;
  const float CE = 0.125f;

  const int ts = tid & 255;
  const int u0 = ts, u1 = ts + 256;
  const int r0 = u0 >> 3, c0 = u0 & 7, r1 = u1 >> 3, c1 = u1 & 7;
  const int sw0 = (c0 ^ (r0 & 7)) * 8, sw1 = (c1 ^ (r1 & 7)) * 8;

  const int qt = (blockIdx.z == 0) ? (int)blockIdx.x : 15 - (int)blockIdx.x;
  const int q0 = qt * 128;
  const int qg = q0 + w * 32 + l31;
  size_t qbase = ((size_t)(b * 2048 + qg)) * 1024 + (size_t)h * 64;
  bf16x8 qf[4];
  #pragma unroll
  for (int ck = 0; ck < 4; ck++)
    qf[ck] = *(const bf16x8*)&qb[qbase + ck * 16 + h2 * 8];

  f32x16 accO[2] = {};
  float mrun = -INFINITY, lrun = 0.0f;

  const int nt = qt + 1;
  const int kt0 = g * nt;

  const ushort* ksrc0 = kb + ((size_t)(b * 2048 + kt0 * 64 + r0)) * 1024 + (size_t)h * 64 + c0 * 8;
  const ushort* ksrc1 = kb + ((size_t)(b * 2048 + kt0 * 64 + r1)) * 1024 + (size_t)h * 64 + c1 * 8;
  const ushort* vsrc0 = vT + ((size_t)((b * 16 + h) * 64 + r0)) * 2048 + kt0 * 64 + c0 * 8;
  const ushort* vsrc1 = vT + ((size_t)((b * 16 + h) * 64 + r1)) * 2048 + kt0 * 64 + c1 * 8;

  uint4 kc0 = *(const uint4*)ksrc0;
  uint4 kc1 = *(const uint4*)ksrc1;
  uint4 vc0 = *(const uint4*)vsrc0;
  uint4 vc1 = *(const uint4*)vsrc1;

  for (int t = 0; t < nt; t++) {
    int kt = kt0 + t;
    __syncthreads();
    *(uint4*)&Ks[r0 * 64 + sw0] = kc0;
    *(uint4*)&Ks[r1 * 64 + sw1] = kc1;
    *(uint4*)&Vs[r0 * 64 + sw0] = vc0;
    *(uint4*)&Vs[r1 * 64 + sw1] = vc1;
    __syncthreads();
    if (t + 1 < nt) {
      kc0 = *(const uint4*)(ksrc0 + (size_t)(t + 1) * 65536);
      kc1 = *(const uint4*)(ksrc1 + (size_t)(t + 1) * 65536);
      vc0 = *(const uint4*)(vsrc0 + (t + 1) * 64);
      vc1 = *(const uint4*)(vsrc1 + (t + 1) * 64);
    }

    bool active = (kt * 64 <= q0 + w * 32 + 31);
    if (active) {
      f32x16 sc[2] = {};
      __builtin_amdgcn_s_setprio(1);
      #pragma unroll
      for (int mf = 0; mf < 2; mf++) {
        int row = mf * 32 + l31;
        int s8 = row & 7;
        #pragma unroll
        for (int ck = 0; ck < 4; ck++) {
          bf16x8 ka = *(const bf16x8*)&Ks[row * 64 + (((2 * ck + h2) ^ s8) * 8)];
          sc[mf] = __builtin_amdgcn_mfma_f32_32x32x16_bf16(ka, qf[ck], sc[mf], 0, 0, 0);
        }
      }
      __builtin_amdgcn_s_setprio(0);

      if (kt * 64 + 63 > q0 + w * 32) {
        #pragma unroll
        for (int mf = 0; mf < 2; mf++)
          #pragma unroll
          for (int i = 0; i < 16; i++) {
            int kv = kt * 64 + mf * 32 + (i & 3) + 8 * (i >> 2) + 4 * h2;
            sc[mf][i] = (kv > qg) ? -8000.0f : sc[mf][i];
          }
      }

      float tm = sc[0][0];
      #pragma unroll
      for (int i = 1; i < 16; i++) tm = fmaxf(tm, sc[0][i]);
      #pragma unroll
      for (int i = 0; i < 16; i++) tm = fmaxf(tm, sc[1][i]);
      tm = fmaxf(tm, __shfl_xor(tm, 32));
      float mnew = fmaxf(mrun, tm);
      float alpha = __expf((mrun - mnew) * CE);
      float p[2][16];
      float rs = 0.0f;
      #pragma unroll
      for (int mf = 0; mf < 2; mf++)
        #pragma unroll
        for (int i = 0; i < 16; i++) {
          float pv = __expf((sc[mf][i] - mnew) * CE);
          p[mf][i] = pv;
          rs += pv;
        }
      rs += __shfl_xor(rs, 32);
      lrun = lrun * alpha + rs;
      mrun = mnew;
      #pragma unroll
      for (int mf = 0; mf < 2; mf++)
        #pragma unroll
        for (int i = 0; i < 16; i++) accO[mf][i] *= alpha;

      #pragma unroll
      for (int mf = 0; mf < 2; mf++)
        #pragma unroll
        for (int m = 0; m < 4; m++) {
          uint2 w2;
          w2.x = pack2bf(p[mf][4 * m + 0], p[mf][4 * m + 1]);
          w2.y = pack2bf(p[mf][4 * m + 2], p[mf][4 * m + 3]);
          *(uint2*)&P2[qrow * 72 + 32 * mf + 8 * m + 4 * h2] = w2;
        }

      __builtin_amdgcn_s_setprio(1);
      #pragma unroll
      for (int ck = 0; ck < 4; ck++) {
        bf16x8 pB = *(const bf16x8*)&P2[qrow * 72 + ck * 16 + h2 * 8];
        #pragma unroll
        for (int mf = 0; mf < 2; mf++) {
          int row = mf * 32 + l31;
          bf16x8 va = *(const bf16x8*)&Vs[row * 64 + (((2 * ck + h2) ^ (row & 7)) * 8)];
          accO[mf] = __builtin_amdgcn_mfma_f32_32x32x16_bf16(va, pB, accO[mf], 0, 0, 0);
        }
      }
      __builtin_amdgcn_s_setprio(0);
    }
  }

  __syncthreads();
  float* mbuf = (float*)sbuf;
  int midx = (w * 64 + lane) * 35;
  if (g == 1) {
    #pragma unroll
    for (int i = 0; i < 16; i++) mbuf[midx + i] = accO[0][i];
    #pragma unroll
    for (int i = 0; i < 16; i++) mbuf[midx + 16 + i] = accO[1][i];
    mbuf[midx + 32] = mrun;
    mbuf[midx + 33] = lrun;
  }
  __syncthreads();
  ushort* Osb = sbuf + 16384 + 9216;
  if (g == 0) {
    float m1 = mbuf[midx + 32], l1 = mbuf[midx + 33];
    float mn = fmaxf(mrun, m1);
    float a0 = __expf((mrun - mn) * CE), a1 = __expf((m1 - mn) * CE);
    float linv = 1.0f / (lrun * a0 + l1 * a1);
    #pragma unroll
    for (int mf = 0; mf < 2; mf++)
      #pragma unroll
      for (int m = 0; m < 4; m++) {
        int e0 = 32 * mf + 8 * m + 4 * h2;
        float o0 = (accO[mf][4 * m + 0] * a0 + mbuf[midx + 16 * mf + 4 * m + 0] * a1) * linv;
        float o1 = (accO[mf][4 * m + 1] * a0 + mbuf[midx + 16 * mf + 4 * m + 1] * a1) * linv;
        float o2 = (accO[mf][4 * m + 2] * a0 + mbuf[midx + 16 * mf + 4 * m + 2] * a1) * linv;
        float o3 = (accO[mf][4 * m + 3] * a0 + mbuf[midx + 16 * mf + 4 * m + 3] * a1) * linv;
        *(unsigned*)&Osb[qrow * 72 + e0] = pack2bf(o0, o1);
        *(unsigned*)&Osb[qrow * 72 + e0 + 2] = pack2bf(o2, o3);
      }
  }
  __syncthreads();
  size_t obase = ((size_t)(b * 2048 + q0)) * 1024 + (size_t)h * 64;
  #pragma unroll
  for (int i = 0; i < 2; i++) {
    int u = tid + i * 512;
    int r = u >> 3, blk = u & 7;
    *(uint4*)&zb[obase + (size_t)r * 1024 + blk * 8] = *(const uint4*)&Osb[r * 72 + blk * 8];
  }
}

extern "C" void kernel_launch(void* const* d_in, const int* in_sizes, int n_in,
                              void* d_out, int out_size, void* d_ws, size_t ws_size,
                              hipStream_t stream) {
  const float* Xq  = (const float*)d_in[0];
  const float* Xk  = (const float*)d_in[1];
  const float* Xv  = (const float*)d_in[2];
  const float* W_Q = (const float*)d_in[3];
  const float* W_K = (const float*)d_in[4];
  const float* W_V = (const float*)d_in[5];
  const float* W_O = (const float*)d_in[6];
  const float* b_Q = (const float*)d_in[7];
  const float* b_K = (const float*)d_in[8];
  const float* b_V = (const float*)d_in[9];
  const float* b_O = (const float*)d_in[10];
  float* out = (float*)d_out;

  char* base = (char*)d_ws;
  float*  amax = (float*)(base + 0);
  float*  amaxpart = (float*)(base + 1024);
  float*  bq   = (float*)(base + 4096);
  float*  bk   = (float*)(base + 8192);
  float*  bv   = (float*)(base + 12288);
  ushort* wq   = (ushort*)(base + 16384);
  ushort* wk   = (ushort*)(base + 16384 + 2097152);
  ushort* wv   = (ushort*)(base + 16384 + 2u * 2097152);
  ushort* woT  = (ushort*)(base + 16384 + 3u * 2097152);
  ushort* xq   = (ushort*)(base + 8404992);
  ushort* xk   = (ushort*)(base + 16793600);
  ushort* xv   = (ushort*)(base + 25182208);
  ushort* qbf  = (ushort*)(base + 33570816);
  ushort* kbf  = (ushort*)(base + 41959424);
  ushort* vT   = (ushort*)(base + 50348032);
  ushort* zbf  = xk;   // xk dead after gemm3_qkv

  prep1<<<12672, 256, 0, stream>>>(W_Q, W_K, W_V, b_Q, b_K, b_V, Xq, Xk, Xv,
                                   amaxpart, xq, xk, xv);
  prep2<<<1036, 256, 0, stream>>>(W_Q, W_K, W_V, W_O, b_Q, b_K, b_V,
                                  amaxpart, amax, wq, wk, wv, woT, bq, bk, bv);
  gemm3_qkv<<<768, 256, 0, stream>>>(xq, xk, xv, wq, wk, wv, bq, bk, bv, amax,
                                     qbf, kbf, vT);
  dim3 fgrid(16, 16, 2);
  flash_mfma9<<<fgrid, 512, 0, stream>>>(qbf, kbf, vT, zbf);
  gemm_wo<<<512, 256, 0, stream>>>(zbf, woT, b_O, out);
}